// Round 21
// baseline (123.960 us; speedup 1.0000x reference)
//
#include <hip/hip_runtime.h>
#include <math.h>
#include <stdint.h>

#define N_NODES 16384
#define N_EDGES 262144
#define HID 128
#define NRBF 20
#define CUTOFF 5.0f
#define PI_F 3.14159265358979323846f

#define CSTRIDE 16

typedef __attribute__((ext_vector_type(2))) __fp16 half2_t;
typedef __attribute__((ext_vector_type(4))) __fp16 v4h;
typedef __attribute__((ext_vector_type(4))) float f32x4;
union U32H2 { uint32_t u; half2_t h; float f; };
union U2H4 { uint32_t u[2]; v4h h; };

__device__ inline unsigned short f2bf(float f) {
    unsigned int u = __float_as_uint(f);
    u = u + 0x7FFFu + ((u >> 16) & 1u);
    return (unsigned short)(u >> 16);
}
__device__ inline uint32_t pack2(float lo, float hi) {
    return (uint32_t)f2bf(lo) | ((uint32_t)f2bf(hi) << 16);
}
__device__ inline float blo(uint32_t u) { return __uint_as_float(u << 16); }
__device__ inline float bhi(uint32_t u) { return __uint_as_float(u & 0xFFFF0000u); }
__device__ inline uint32_t pkh2(float a, float b) {
    U32H2 u; u.h = __builtin_amdgcn_cvt_pkrtz(a, b); return u.u;
}

// ---------------------------------------------------------------------------
// Kernel 0: prep — pack weights into MFMA B-fragment order + edge histogram.
// B-frag (16x16x16 f16): lane l holds B[k = ks*16 + 4*(l>>4) + j][col], j=0..3,
// col = ctile*16 + (l&15). Layout VERIFIED (R19/R20, absmax 0.5).
// cnt must be pre-zeroed.
// ids: [0,8192) W1f | [8192,32768) W2f | [32768,36608) Wrbfp |
//      [36608,298752) histogram
// ---------------------------------------------------------------------------
__global__ __launch_bounds__(256) void prep_kernel(
    const float* __restrict__ W1, const float* __restrict__ W2,
    const float* __restrict__ Wrbf, const int* __restrict__ edst,
    int* __restrict__ cnt, uint32_t* __restrict__ W1f,
    uint32_t* __restrict__ W2f, uint32_t* __restrict__ Wrbfp)
{
    const int id = blockIdx.x * 256 + threadIdx.x;
    if (id < 8192) {
        const int c = id >> 10, rem = id & 1023;
        const int ks = rem >> 7, l = (rem & 127) >> 1, p = rem & 1;
        const int k = ks * 16 + 4 * (l >> 4) + 2 * p;
        const int col = c * 16 + (l & 15);
        W1f[id] = pkh2(W1[(size_t)k * 128 + col], W1[(size_t)(k + 1) * 128 + col]);
    } else if (id < 32768) {
        const int i = id - 8192;
        const int c = i >> 10, rem = i & 1023;
        const int ks = rem >> 7, l = (rem & 127) >> 1, p = rem & 1;
        const int k = ks * 16 + 4 * (l >> 4) + 2 * p;
        const int col = c * 16 + (l & 15);
        W2f[i] = pkh2(W2[(size_t)k * 384 + col], W2[(size_t)(k + 1) * 384 + col]);
    } else if (id < 36608) {
        const int i = id - 32768;
        const int j = i / 384, rem = i % 384;
        Wrbfp[i] = pkh2(Wrbf[(size_t)(2 * j) * 384 + rem],
                        Wrbf[(size_t)(2 * j + 1) * 384 + rem]);
    } else if (id < 36608 + N_EDGES) {
        atomicAdd(&cnt[edst[id - 36608]], 1);
    }
}

// ---------------------------------------------------------------------------
// CSR scan
// ---------------------------------------------------------------------------
__global__ __launch_bounds__(256) void scan_kernel(const int* __restrict__ cnt,
                                                   int* __restrict__ row_ptr,
                                                   int* __restrict__ cur)
{
    __shared__ int part[256];
    const int tid = threadIdx.x;
    const int4* c4 = (const int4*)cnt;

    int4 loc[16];
    int s = 0;
    #pragma unroll
    for (int j = 0; j < 16; ++j) {
        loc[j] = c4[tid * 16 + j];
        s += loc[j].x + loc[j].y + loc[j].z + loc[j].w;
    }
    part[tid] = s;
    __syncthreads();
    #pragma unroll
    for (int d = 1; d < 256; d <<= 1) {
        const int add = (tid >= d) ? part[tid - d] : 0;
        __syncthreads();
        part[tid] += add;
        __syncthreads();
    }
    int off = (tid == 0) ? 0 : part[tid - 1];
    const int base = tid * 64;
    #pragma unroll
    for (int j = 0; j < 16; ++j) {
        const int4 q = loc[j];
        row_ptr[base + j*4 + 0] = off; cur[base + j*4 + 0] = off; off += q.x;
        row_ptr[base + j*4 + 1] = off; cur[base + j*4 + 1] = off; off += q.y;
        row_ptr[base + j*4 + 2] = off; cur[base + j*4 + 2] = off; off += q.z;
        row_ptr[base + j*4 + 3] = off; cur[base + j*4 + 3] = off; off += q.w;
    }
    if (tid == 255) row_ptr[16384] = off;
}

// ---------------------------------------------------------------------------
// Kernel 2 (FUSED): scatter (256 edges/block, 1 per thread, native trig)
// then MFMA phi (16 nodes/block, 4 waves split the 8/24 column tiles).
// 1024 blocks x 256 threads -> 4 blocks/CU.
// ---------------------------------------------------------------------------
__global__ __launch_bounds__(256) void phi_scatter_kernel(
    const float* __restrict__ s, const float* __restrict__ v,
    const uint32_t* __restrict__ W1f, const float* __restrict__ b1,
    const uint32_t* __restrict__ W2f, const float* __restrict__ b2,
    const float* __restrict__ r_ij, const int* __restrict__ esrc,
    const int* __restrict__ edst, int* __restrict__ cur,
    int* __restrict__ soff, uint32_t* __restrict__ coef,
    uint2* __restrict__ guv, uint32_t* __restrict__ gw)
{
    const int tid = threadIdx.x;
    const int l  = tid & 63;          // lane
    const int w  = tid >> 6;          // wave 0..3
    const int r  = l & 15;            // row/col within 16-tile
    const int g4 = l >> 4;            // 0..3
    const int node0 = blockIdx.x * 16;

    // ---- scatter phase: one edge per thread, native v_sin/v_cos ------------
    {
        const int e = blockIdx.x * 256 + tid;
        const float rx = r_ij[(size_t)e * 3 + 0];
        const float ry = r_ij[(size_t)e * 3 + 1];
        const float rz = r_ij[(size_t)e * 3 + 2];
        const float d = sqrtf(rx * rx + ry * ry + rz * rz);
        const float inv_d = 1.0f / d;
        const float x = (PI_F / CUTOFF) * d;
        const float sx = __sinf(x);
        const float cx = __cosf(x);
        const float fcut = (d < CUTOFF) ? 0.5f * (cx + 1.0f) : 0.0f;

        float cf[NRBF];
        const float gfac = inv_d * fcut;
        const float twocx = 2.0f * cx;
        float sm1 = sx, sm2 = 0.0f;
        cf[0] = sx * gfac;
        #pragma unroll
        for (int n = 1; n < NRBF; ++n) {
            const float sn = twocx * sm1 - sm2;
            sm2 = sm1; sm1 = sn;
            cf[n] = sn * gfac;
        }

        uint32_t cp[10];
        #pragma unroll
        for (int j = 0; j < 10; ++j) cp[j] = pkh2(cf[2 * j], cf[2 * j + 1]);

        const int pos = atomicAdd(&cur[edst[e]], 1);
        soff[pos] = esrc[e] * 128;
        uint4* c4 = (uint4*)(coef + (size_t)pos * CSTRIDE);
        c4[0] = make_uint4(__float_as_uint(rx * inv_d),
                           __float_as_uint(ry * inv_d),
                           __float_as_uint(rz * inv_d),
                           __float_as_uint(fcut));
        c4[1] = make_uint4(cp[0], cp[1], cp[2], cp[3]);
        c4[2] = make_uint4(cp[4], cp[5], cp[6], cp[7]);
        c4[3] = make_uint4(cp[8], cp[9], 0u, 0u);
    }

    // ---- GEMM1: H = silu(S @ W1 + b1); wave w computes ctiles 2w, 2w+1 -----
    __shared__ float hL[16][132];     // +4 pad breaks bank alias (8.4 KB)

    uint32_t a1f[16];
    #pragma unroll
    for (int ks = 0; ks < 8; ++ks) {
        const float4 sv = *(const float4*)
            &s[(size_t)(node0 + r) * HID + ks * 16 + 4 * g4];
        a1f[2 * ks]     = pkh2(sv.x, sv.y);
        a1f[2 * ks + 1] = pkh2(sv.z, sv.w);
    }

    #pragma unroll
    for (int cc = 0; cc < 2; ++cc) {
        const int c = w * 2 + cc;
        f32x4 acc = (f32x4){0.f, 0.f, 0.f, 0.f};
        #pragma unroll
        for (int ks = 0; ks < 8; ++ks) {
            U2H4 af; af.u[0] = a1f[2 * ks]; af.u[1] = a1f[2 * ks + 1];
            const uint2 bw = *(const uint2*)&W1f[((c * 8 + ks) * 64 + l) * 2];
            U2H4 bf; bf.u[0] = bw.x; bf.u[1] = bw.y;
            acc = __builtin_amdgcn_mfma_f32_16x16x16f16(af.h, bf.h, acc, 0, 0, 0);
        }
        const float bb = b1[c * 16 + r];
        #pragma unroll
        for (int j = 0; j < 4; ++j) {
            const float x = acc[j] + bb;
            hL[4 * g4 + j][c * 16 + r] = x / (1.0f + __expf(-x));
        }
    }
    __syncthreads();

    // ---- GEMM2: PHI = H @ W2 + b2; wave w computes ch-groups 2w, 2w+1 ------
    uint32_t a2f[16];
    #pragma unroll
    for (int ks = 0; ks < 8; ++ks) {
        const float4 hv = *(const float4*)&hL[r][ks * 16 + 4 * g4];
        a2f[2 * ks]     = pkh2(hv.x, hv.y);
        a2f[2 * ks + 1] = pkh2(hv.z, hv.w);
    }

    #pragma unroll
    for (int cc = 0; cc < 2; ++cc) {
        const int c = w * 2 + cc;
        f32x4 pA = (f32x4){0.f, 0.f, 0.f, 0.f};
        f32x4 pB = (f32x4){0.f, 0.f, 0.f, 0.f};
        f32x4 pC = (f32x4){0.f, 0.f, 0.f, 0.f};
        #pragma unroll
        for (int ks = 0; ks < 8; ++ks) {
            U2H4 af; af.u[0] = a2f[2 * ks]; af.u[1] = a2f[2 * ks + 1];
            const uint2 b0w = *(const uint2*)&W2f[(((c     ) * 8 + ks) * 64 + l) * 2];
            const uint2 b1w = *(const uint2*)&W2f[(((c +  8) * 8 + ks) * 64 + l) * 2];
            const uint2 b2w = *(const uint2*)&W2f[(((c + 16) * 8 + ks) * 64 + l) * 2];
            U2H4 bf0; bf0.u[0] = b0w.x; bf0.u[1] = b0w.y;
            U2H4 bf1; bf1.u[0] = b1w.x; bf1.u[1] = b1w.y;
            U2H4 bf2; bf2.u[0] = b2w.x; bf2.u[1] = b2w.y;
            pA = __builtin_amdgcn_mfma_f32_16x16x16f16(af.h, bf0.h, pA, 0, 0, 0);
            pB = __builtin_amdgcn_mfma_f32_16x16x16f16(af.h, bf1.h, pB, 0, 0, 0);
            pC = __builtin_amdgcn_mfma_f32_16x16x16f16(af.h, bf2.h, pC, 0, 0, 0);
        }
        const int ch = c * 16 + r;
        const float bbA = b2[ch];
        const float bbB = b2[128 + ch];
        const float bbC = b2[256 + ch];
        #pragma unroll
        for (int j = 0; j < 4; ++j) {
            const int node = node0 + 4 * g4 + j;
            const size_t nrow = (size_t)node * 384;
            const float p0 = pA[j] + bbA;
            const float p1 = pB[j] + bbB;
            const float p2 = pC[j] + bbC;
            const float v0 = v[nrow + ch];
            const float v1 = v[nrow + 128 + ch];
            const float v2 = v[nrow + 256 + ch];
            const size_t gi = (size_t)node * HID + ch;
            guv[gi] = make_uint2(pack2(p0, p1), pack2(p2, v0));
            gw[gi]  = pack2(v1, v2);
        }
    }
}

// ---------------------------------------------------------------------------
// Gather: EXACT R14 configuration (72 us, no spills): node per 128-thread
// group; batch-4 edges; depth-2 ping-pong; uint2+u32 12 B gathers; scalar
// coef/soff loads + K$ warm; fdot2 on pre-packed weights pinned via asm.
// launch_bounds(256,6). DO NOT: raise waves/EU (R15 spill), deepen prefetch
// (R13 spill), or merge loads into uint3 (R16 scratch pathology).
// ---------------------------------------------------------------------------
__global__ __launch_bounds__(256, 6) void gather_kernel(
    const uint2* __restrict__ guv, const uint32_t* __restrict__ gw,
    const int* __restrict__ soff, const uint32_t* __restrict__ coef,
    const int* __restrict__ row_ptr, const uint32_t* __restrict__ Wrbfp,
    const float* __restrict__ brbf,
    float* __restrict__ dv, float* __restrict__ ds)
{
    const int ch   = threadIdx.x & 127;
    const int node = blockIdx.x * 2 + (threadIdx.x >> 7);

    uint32_t wq0[10], wq1[10], wq2[10];
    #pragma unroll
    for (int j = 0; j < 10; ++j) {
        wq0[j] = Wrbfp[(j * 3 + 0) * 128 + ch];
        wq1[j] = Wrbfp[(j * 3 + 1) * 128 + ch];
        wq2[j] = Wrbfp[(j * 3 + 2) * 128 + ch];
    }
    #pragma unroll
    for (int j = 0; j < 10; ++j) {
        asm volatile("" : "+v"(wq0[j]), "+v"(wq1[j]), "+v"(wq2[j]));
    }
    const float br0 = brbf[ch], br1 = brbf[128 + ch], br2 = brbf[256 + ch];

    const int beg = row_ptr[node];
    const int end = row_ptr[node + 1];
    const int nb  = (end - beg) >> 2;

    float a0 = 0.f, a1 = 0.f, a2 = 0.f, as = 0.f;

    uint2 A2[4], B2[4];
    uint32_t Aw[4], Bw[4];

#define LOADB(P2, Pw, bi) do {                                                \
    const int iu_ = __builtin_amdgcn_readfirstlane(beg + (bi) * 4);           \
    const int* sp_ = soff + iu_;                                              \
    const int o0 = sp_[0] + ch, o1 = sp_[1] + ch,                             \
              o2 = sp_[2] + ch, o3 = sp_[3] + ch;                             \
    P2[0] = guv[o0]; P2[1] = guv[o1]; P2[2] = guv[o2]; P2[3] = guv[o3];       \
    Pw[0] = gw[o0];  Pw[1] = gw[o1];  Pw[2] = gw[o2];  Pw[3] = gw[o3];        \
    const uint32_t* cq_ = coef + (size_t)iu_ * CSTRIDE;                       \
    const uint32_t t0_ = cq_[0],  t1_ = cq_[16],                              \
                   t2_ = cq_[32], t3_ = cq_[48];                              \
    asm volatile("" :: "s"(t0_), "s"(t1_), "s"(t2_), "s"(t3_));               \
} while (0)

#define CONSUME(P2, Pw, bi) do {                                              \
    const uint32_t* cp_ = coef +                                              \
        (size_t)__builtin_amdgcn_readfirstlane(beg + (bi) * 4) * CSTRIDE;     \
    _Pragma("unroll")                                                         \
    for (int k = 0; k < 4; ++k) {                                             \
        const float ux = __uint_as_float(cp_[k * CSTRIDE + 0]);               \
        const float uy = __uint_as_float(cp_[k * CSTRIDE + 1]);               \
        const float uz = __uint_as_float(cp_[k * CSTRIDE + 2]);               \
        const float fc = __uint_as_float(cp_[k * CSTRIDE + 3]);               \
        float W0 = fc * br0;                                                  \
        float W1 = fc * br1;                                                  \
        float W2 = fc * br2;                                                  \
        _Pragma("unroll")                                                     \
        for (int j = 0; j < 10; ++j) {                                        \
            U32H2 cc; cc.u = cp_[k * CSTRIDE + 4 + j];                        \
            U32H2 w0_; w0_.u = wq0[j];                                        \
            U32H2 w1_; w1_.u = wq1[j];                                        \
            U32H2 w2_; w2_.u = wq2[j];                                        \
            W0 = __builtin_amdgcn_fdot2(cc.h, w0_.h, W0, false);              \
            W1 = __builtin_amdgcn_fdot2(cc.h, w1_.h, W1, false);              \
            W2 = __builtin_amdgcn_fdot2(cc.h, w2_.h, W2, false);              \
        }                                                                     \
        const uint32_t p0 = P2[k].x, p1 = P2[k].y, p2 = Pw[k];                \
        const float xv = blo(p0) * W0;                                        \
        const float xs = bhi(p0) * W1;                                        \
        const float xd = blo(p1) * W2;                                        \
        a0 += bhi(p1) * xv + ux * xd;                                         \
        a1 += blo(p2) * xv + uy * xd;                                         \
        a2 += bhi(p2) * xv + uz * xd;                                         \
        as += xs;                                                             \
    }                                                                         \
} while (0)

    if (nb > 0) {
        const int last = nb - 1;
        LOADB(A2, Aw, 0);
        LOADB(B2, Bw, (1 < last ? 1 : last));
        int b = 0;
        for (; b + 2 < nb; b += 2) {
            CONSUME(A2, Aw, b);
            LOADB(A2, Aw, b + 2);
            CONSUME(B2, Bw, b + 1);
            LOADB(B2, Bw, (b + 3 < last ? b + 3 : last));
        }
        const int rem = nb - b;
        CONSUME(A2, Aw, b);
        if (rem == 2) CONSUME(B2, Bw, b + 1);
    }

    // tail (0..3 edges)
    for (int i = beg + (nb << 2); i < end; ++i) {
        const int iu = __builtin_amdgcn_readfirstlane(i);
        const int o = soff[iu] + ch;
        const uint2 P = guv[o];
        const uint32_t p2 = gw[o];
        const uint32_t* cp = coef + (size_t)iu * CSTRIDE;
        const float ux = __uint_as_float(cp[0]);
        const float uy = __uint_as_float(cp[1]);
        const float uz = __uint_as_float(cp[2]);
        const float fc = __uint_as_float(cp[3]);
        float W0 = fc * br0;
        float W1 = fc * br1;
        float W2 = fc * br2;
        #pragma unroll
        for (int j = 0; j < 10; ++j) {
            U32H2 cc; cc.u = cp[4 + j];
            U32H2 w0_; w0_.u = wq0[j];
            U32H2 w1_; w1_.u = wq1[j];
            U32H2 w2_; w2_.u = wq2[j];
            W0 = __builtin_amdgcn_fdot2(cc.h, w0_.h, W0, false);
            W1 = __builtin_amdgcn_fdot2(cc.h, w1_.h, W1, false);
            W2 = __builtin_amdgcn_fdot2(cc.h, w2_.h, W2, false);
        }
        const uint32_t p0 = P.x, p1 = P.y;
        const float xv = blo(p0) * W0;
        const float xs = bhi(p0) * W1;
        const float xd = blo(p1) * W2;
        a0 += bhi(p1) * xv + ux * xd;
        a1 += blo(p2) * xv + uy * xd;
        a2 += bhi(p2) * xv + uz * xd;
        as += xs;
    }

#undef LOADB
#undef CONSUME

    const size_t orow = (size_t)node * 384;
    dv[orow + ch]       = a0;
    dv[orow + 128 + ch] = a1;
    dv[orow + 256 + ch] = a2;
    ds[(size_t)node * HID + ch] = as;
}

extern "C" void kernel_launch(void* const* d_in, const int* in_sizes, int n_in,
                              void* d_out, int out_size, void* d_ws, size_t ws_size,
                              hipStream_t stream)
{
    const float* s    = (const float*)d_in[0];
    const float* v    = (const float*)d_in[1];
    const float* r_ij = (const float*)d_in[2];
    const int*   esrc = (const int*)d_in[3];
    const int*   edst = (const int*)d_in[4];
    const float* W1   = (const float*)d_in[5];
    const float* b1   = (const float*)d_in[6];
    const float* W2   = (const float*)d_in[7];
    const float* b2   = (const float*)d_in[8];
    const float* Wrbf = (const float*)d_in[9];
    const float* brbf = (const float*)d_in[10];

    float* out = (float*)d_out;
    float* dv  = out;                                   // (16384,3,128)
    float* ds  = out + (size_t)N_NODES * 3 * HID;       // (16384,128)

    // workspace layout — pad after row_ptr so row_ptr[16384] cannot alias
    // cur[0] (the R4 crash).
    char* ws = (char*)d_ws;
    uint2*    guv     = (uint2*)   (ws + 0);            // 16,777,216 B
    uint32_t* gw      = (uint32_t*)(ws + 16777216);     //  8,388,608 B
    uint32_t* coef    = (uint32_t*)(ws + 25165824);     // 16,777,216 B
    int*      soff    = (int*)     (ws + 41943040);     //  1,048,576 B
    int*      cnt     = (int*)     (ws + 42991616);     //     65,536 B
    int*      row_ptr = (int*)     (ws + 43057152);     //     65,540 B used
    int*      cur     = (int*)     (ws + 43122816);     //     65,536 B
    uint32_t* W1f     = (uint32_t*)(ws + 43188352);     //     32,768 B
    uint32_t* W2f     = (uint32_t*)(ws + 43221120);     //     98,304 B
    uint32_t* Wrbfp   = (uint32_t*)(ws + 43319424);     //     15,360 B

    hipMemsetAsync(cnt, 0, 16384 * sizeof(int), stream);

    prep_kernel<<<1167, 256, 0, stream>>>(W1, W2, Wrbf, edst, cnt,
                                          W1f, W2f, Wrbfp);
    scan_kernel<<<1, 256, 0, stream>>>(cnt, row_ptr, cur);
    phi_scatter_kernel<<<1024, 256, 0, stream>>>(s, v, W1f, b1, W2f, b2,
                                                 r_ij, esrc, edst, cur,
                                                 soff, coef, guv, gw);
    gather_kernel<<<N_NODES / 2, 256, 0, stream>>>(guv, gw, soff, coef, row_ptr,
                                                   Wrbfp, brbf, dv, ds);
}

// Round 22
// 122.325 us; speedup vs baseline: 1.0134x; 1.0134x over previous
//
#include <hip/hip_runtime.h>
#include <math.h>
#include <stdint.h>

#define N_NODES 16384
#define N_EDGES 262144
#define HID 128
#define NRBF 20
#define CUTOFF 5.0f
#define PI_F 3.14159265358979323846f

#define CSTRIDE 16

typedef __attribute__((ext_vector_type(2))) __fp16 half2_t;
typedef __attribute__((ext_vector_type(4))) __fp16 v4h;
typedef __attribute__((ext_vector_type(4))) float f32x4;
union U32H2 { uint32_t u; half2_t h; float f; };
union U2H4 { uint32_t u[2]; v4h h; };

__device__ inline unsigned short f2bf(float f) {
    unsigned int u = __float_as_uint(f);
    u = u + 0x7FFFu + ((u >> 16) & 1u);
    return (unsigned short)(u >> 16);
}
__device__ inline uint32_t pack2(float lo, float hi) {
    return (uint32_t)f2bf(lo) | ((uint32_t)f2bf(hi) << 16);
}
__device__ inline float blo(uint32_t u) { return __uint_as_float(u << 16); }
__device__ inline float bhi(uint32_t u) { return __uint_as_float(u & 0xFFFF0000u); }
__device__ inline uint32_t pkh2(float a, float b) {
    U32H2 u; u.h = __builtin_amdgcn_cvt_pkrtz(a, b); return u.u;
}

// ---------------------------------------------------------------------------
// Kernel 0: prep — pack weights into MFMA B-fragment order + edge histogram.
// B-frag (16x16x16 f16): lane l holds B[k = ks*16 + 4*(l>>4) + j][col], j=0..3,
// col = ctile*16 + (l&15). Layout VERIFIED (R19/R20, absmax 0.5).
// cnt must be pre-zeroed.
// ids: [0,8192) W1f | [8192,32768) W2f | [32768,36608) Wrbfp |
//      [36608,298752) histogram
// ---------------------------------------------------------------------------
__global__ __launch_bounds__(256) void prep_kernel(
    const float* __restrict__ W1, const float* __restrict__ W2,
    const float* __restrict__ Wrbf, const int* __restrict__ edst,
    int* __restrict__ cnt, uint32_t* __restrict__ W1f,
    uint32_t* __restrict__ W2f, uint32_t* __restrict__ Wrbfp)
{
    const int id = blockIdx.x * 256 + threadIdx.x;
    if (id < 8192) {
        const int c = id >> 10, rem = id & 1023;
        const int ks = rem >> 7, l = (rem & 127) >> 1, p = rem & 1;
        const int k = ks * 16 + 4 * (l >> 4) + 2 * p;
        const int col = c * 16 + (l & 15);
        W1f[id] = pkh2(W1[(size_t)k * 128 + col], W1[(size_t)(k + 1) * 128 + col]);
    } else if (id < 32768) {
        const int i = id - 8192;
        const int c = i >> 10, rem = i & 1023;
        const int ks = rem >> 7, l = (rem & 127) >> 1, p = rem & 1;
        const int k = ks * 16 + 4 * (l >> 4) + 2 * p;
        const int col = c * 16 + (l & 15);
        W2f[i] = pkh2(W2[(size_t)k * 384 + col], W2[(size_t)(k + 1) * 384 + col]);
    } else if (id < 36608) {
        const int i = id - 32768;
        const int j = i / 384, rem = i % 384;
        Wrbfp[i] = pkh2(Wrbf[(size_t)(2 * j) * 384 + rem],
                        Wrbf[(size_t)(2 * j + 1) * 384 + rem]);
    } else if (id < 36608 + N_EDGES) {
        atomicAdd(&cnt[edst[id - 36608]], 1);
    }
}

// ---------------------------------------------------------------------------
// CSR scan
// ---------------------------------------------------------------------------
__global__ __launch_bounds__(256) void scan_kernel(const int* __restrict__ cnt,
                                                   int* __restrict__ row_ptr,
                                                   int* __restrict__ cur)
{
    __shared__ int part[256];
    const int tid = threadIdx.x;
    const int4* c4 = (const int4*)cnt;

    int4 loc[16];
    int s = 0;
    #pragma unroll
    for (int j = 0; j < 16; ++j) {
        loc[j] = c4[tid * 16 + j];
        s += loc[j].x + loc[j].y + loc[j].z + loc[j].w;
    }
    part[tid] = s;
    __syncthreads();
    #pragma unroll
    for (int d = 1; d < 256; d <<= 1) {
        const int add = (tid >= d) ? part[tid - d] : 0;
        __syncthreads();
        part[tid] += add;
        __syncthreads();
    }
    int off = (tid == 0) ? 0 : part[tid - 1];
    const int base = tid * 64;
    #pragma unroll
    for (int j = 0; j < 16; ++j) {
        const int4 q = loc[j];
        row_ptr[base + j*4 + 0] = off; cur[base + j*4 + 0] = off; off += q.x;
        row_ptr[base + j*4 + 1] = off; cur[base + j*4 + 1] = off; off += q.y;
        row_ptr[base + j*4 + 2] = off; cur[base + j*4 + 2] = off; off += q.z;
        row_ptr[base + j*4 + 3] = off; cur[base + j*4 + 3] = off; off += q.w;
    }
    if (tid == 255) row_ptr[16384] = off;
}

// ---------------------------------------------------------------------------
// Kernel 2 (FUSED): scatter (256 edges/block, 1 per thread) then MFMA phi
// (16 nodes/block, 4 waves split the 8/24 column tiles).
// 1024 blocks x 256 threads -> 4 blocks/CU (R19 showed 1 block/CU destroys
// the scatter phase's TLP; R21 showed native trig is neutral -> keep libm).
// ---------------------------------------------------------------------------
__global__ __launch_bounds__(256) void phi_scatter_kernel(
    const float* __restrict__ s, const float* __restrict__ v,
    const uint32_t* __restrict__ W1f, const float* __restrict__ b1,
    const uint32_t* __restrict__ W2f, const float* __restrict__ b2,
    const float* __restrict__ r_ij, const int* __restrict__ esrc,
    const int* __restrict__ edst, int* __restrict__ cur,
    int* __restrict__ soff, uint32_t* __restrict__ coef,
    uint2* __restrict__ guv, uint32_t* __restrict__ gw)
{
    const int tid = threadIdx.x;
    const int l  = tid & 63;          // lane
    const int w  = tid >> 6;          // wave 0..3
    const int r  = l & 15;            // row/col within 16-tile
    const int g4 = l >> 4;            // 0..3
    const int node0 = blockIdx.x * 16;

    // ---- scatter phase: one edge per thread --------------------------------
    {
        const int e = blockIdx.x * 256 + tid;
        const float rx = r_ij[(size_t)e * 3 + 0];
        const float ry = r_ij[(size_t)e * 3 + 1];
        const float rz = r_ij[(size_t)e * 3 + 2];
        const float d = sqrtf(rx * rx + ry * ry + rz * rz);
        const float inv_d = 1.0f / d;
        float sx, cx;
        sincosf((PI_F / CUTOFF) * d, &sx, &cx);
        const float fcut = (d < CUTOFF) ? 0.5f * (cx + 1.0f) : 0.0f;

        float cf[NRBF];
        const float gfac = inv_d * fcut;
        const float twocx = 2.0f * cx;
        float sm1 = sx, sm2 = 0.0f;
        cf[0] = sx * gfac;
        #pragma unroll
        for (int n = 1; n < NRBF; ++n) {
            const float sn = twocx * sm1 - sm2;
            sm2 = sm1; sm1 = sn;
            cf[n] = sn * gfac;
        }

        uint32_t cp[10];
        #pragma unroll
        for (int j = 0; j < 10; ++j) cp[j] = pkh2(cf[2 * j], cf[2 * j + 1]);

        const int pos = atomicAdd(&cur[edst[e]], 1);
        soff[pos] = esrc[e] * 128;
        uint4* c4 = (uint4*)(coef + (size_t)pos * CSTRIDE);
        c4[0] = make_uint4(__float_as_uint(rx * inv_d),
                           __float_as_uint(ry * inv_d),
                           __float_as_uint(rz * inv_d),
                           __float_as_uint(fcut));
        c4[1] = make_uint4(cp[0], cp[1], cp[2], cp[3]);
        c4[2] = make_uint4(cp[4], cp[5], cp[6], cp[7]);
        c4[3] = make_uint4(cp[8], cp[9], 0u, 0u);
    }

    // ---- GEMM1: H = silu(S @ W1 + b1); wave w computes ctiles 2w, 2w+1 -----
    __shared__ float hL[16][132];     // +4 pad breaks bank alias (8.4 KB)

    uint32_t a1f[16];
    #pragma unroll
    for (int ks = 0; ks < 8; ++ks) {
        const float4 sv = *(const float4*)
            &s[(size_t)(node0 + r) * HID + ks * 16 + 4 * g4];
        a1f[2 * ks]     = pkh2(sv.x, sv.y);
        a1f[2 * ks + 1] = pkh2(sv.z, sv.w);
    }

    #pragma unroll
    for (int cc = 0; cc < 2; ++cc) {
        const int c = w * 2 + cc;
        f32x4 acc = (f32x4){0.f, 0.f, 0.f, 0.f};
        #pragma unroll
        for (int ks = 0; ks < 8; ++ks) {
            U2H4 af; af.u[0] = a1f[2 * ks]; af.u[1] = a1f[2 * ks + 1];
            const uint2 bw = *(const uint2*)&W1f[((c * 8 + ks) * 64 + l) * 2];
            U2H4 bf; bf.u[0] = bw.x; bf.u[1] = bw.y;
            acc = __builtin_amdgcn_mfma_f32_16x16x16f16(af.h, bf.h, acc, 0, 0, 0);
        }
        const float bb = b1[c * 16 + r];
        #pragma unroll
        for (int j = 0; j < 4; ++j) {
            const float x = acc[j] + bb;
            hL[4 * g4 + j][c * 16 + r] = x / (1.0f + expf(-x));
        }
    }
    __syncthreads();

    // ---- GEMM2: PHI = H @ W2 + b2; wave w computes ch-groups 2w, 2w+1 ------
    uint32_t a2f[16];
    #pragma unroll
    for (int ks = 0; ks < 8; ++ks) {
        const float4 hv = *(const float4*)&hL[r][ks * 16 + 4 * g4];
        a2f[2 * ks]     = pkh2(hv.x, hv.y);
        a2f[2 * ks + 1] = pkh2(hv.z, hv.w);
    }

    #pragma unroll
    for (int cc = 0; cc < 2; ++cc) {
        const int c = w * 2 + cc;
        f32x4 pA = (f32x4){0.f, 0.f, 0.f, 0.f};
        f32x4 pB = (f32x4){0.f, 0.f, 0.f, 0.f};
        f32x4 pC = (f32x4){0.f, 0.f, 0.f, 0.f};
        #pragma unroll
        for (int ks = 0; ks < 8; ++ks) {
            U2H4 af; af.u[0] = a2f[2 * ks]; af.u[1] = a2f[2 * ks + 1];
            const uint2 b0w = *(const uint2*)&W2f[(((c     ) * 8 + ks) * 64 + l) * 2];
            const uint2 b1w = *(const uint2*)&W2f[(((c +  8) * 8 + ks) * 64 + l) * 2];
            const uint2 b2w = *(const uint2*)&W2f[(((c + 16) * 8 + ks) * 64 + l) * 2];
            U2H4 bf0; bf0.u[0] = b0w.x; bf0.u[1] = b0w.y;
            U2H4 bf1; bf1.u[0] = b1w.x; bf1.u[1] = b1w.y;
            U2H4 bf2; bf2.u[0] = b2w.x; bf2.u[1] = b2w.y;
            pA = __builtin_amdgcn_mfma_f32_16x16x16f16(af.h, bf0.h, pA, 0, 0, 0);
            pB = __builtin_amdgcn_mfma_f32_16x16x16f16(af.h, bf1.h, pB, 0, 0, 0);
            pC = __builtin_amdgcn_mfma_f32_16x16x16f16(af.h, bf2.h, pC, 0, 0, 0);
        }
        const int ch = c * 16 + r;
        const float bbA = b2[ch];
        const float bbB = b2[128 + ch];
        const float bbC = b2[256 + ch];
        #pragma unroll
        for (int j = 0; j < 4; ++j) {
            const int node = node0 + 4 * g4 + j;
            const size_t nrow = (size_t)node * 384;
            const float p0 = pA[j] + bbA;
            const float p1 = pB[j] + bbB;
            const float p2 = pC[j] + bbC;
            const float v0 = v[nrow + ch];
            const float v1 = v[nrow + 128 + ch];
            const float v2 = v[nrow + 256 + ch];
            const size_t gi = (size_t)node * HID + ch;
            guv[gi] = make_uint2(pack2(p0, p1), pack2(p2, v0));
            gw[gi]  = pack2(v1, v2);
        }
    }
}

// ---------------------------------------------------------------------------
// Gather: EXACT R14 configuration (72 us, no spills): node per 128-thread
// group; batch-4 edges; depth-2 ping-pong; uint2+u32 12 B gathers; scalar
// coef/soff loads + K$ warm; fdot2 on pre-packed weights pinned via asm.
// launch_bounds(256,6). DO NOT: raise waves/EU (R15 spill), deepen prefetch
// (R13 spill), or merge loads into uint3 (R16 scratch pathology).
// ---------------------------------------------------------------------------
__global__ __launch_bounds__(256, 6) void gather_kernel(
    const uint2* __restrict__ guv, const uint32_t* __restrict__ gw,
    const int* __restrict__ soff, const uint32_t* __restrict__ coef,
    const int* __restrict__ row_ptr, const uint32_t* __restrict__ Wrbfp,
    const float* __restrict__ brbf,
    float* __restrict__ dv, float* __restrict__ ds)
{
    const int ch   = threadIdx.x & 127;
    const int node = blockIdx.x * 2 + (threadIdx.x >> 7);

    uint32_t wq0[10], wq1[10], wq2[10];
    #pragma unroll
    for (int j = 0; j < 10; ++j) {
        wq0[j] = Wrbfp[(j * 3 + 0) * 128 + ch];
        wq1[j] = Wrbfp[(j * 3 + 1) * 128 + ch];
        wq2[j] = Wrbfp[(j * 3 + 2) * 128 + ch];
    }
    #pragma unroll
    for (int j = 0; j < 10; ++j) {
        asm volatile("" : "+v"(wq0[j]), "+v"(wq1[j]), "+v"(wq2[j]));
    }
    const float br0 = brbf[ch], br1 = brbf[128 + ch], br2 = brbf[256 + ch];

    const int beg = row_ptr[node];
    const int end = row_ptr[node + 1];
    const int nb  = (end - beg) >> 2;

    float a0 = 0.f, a1 = 0.f, a2 = 0.f, as = 0.f;

    uint2 A2[4], B2[4];
    uint32_t Aw[4], Bw[4];

#define LOADB(P2, Pw, bi) do {                                                \
    const int iu_ = __builtin_amdgcn_readfirstlane(beg + (bi) * 4);           \
    const int* sp_ = soff + iu_;                                              \
    const int o0 = sp_[0] + ch, o1 = sp_[1] + ch,                             \
              o2 = sp_[2] + ch, o3 = sp_[3] + ch;                             \
    P2[0] = guv[o0]; P2[1] = guv[o1]; P2[2] = guv[o2]; P2[3] = guv[o3];       \
    Pw[0] = gw[o0];  Pw[1] = gw[o1];  Pw[2] = gw[o2];  Pw[3] = gw[o3];        \
    const uint32_t* cq_ = coef + (size_t)iu_ * CSTRIDE;                       \
    const uint32_t t0_ = cq_[0],  t1_ = cq_[16],                              \
                   t2_ = cq_[32], t3_ = cq_[48];                              \
    asm volatile("" :: "s"(t0_), "s"(t1_), "s"(t2_), "s"(t3_));               \
} while (0)

#define CONSUME(P2, Pw, bi) do {                                              \
    const uint32_t* cp_ = coef +                                              \
        (size_t)__builtin_amdgcn_readfirstlane(beg + (bi) * 4) * CSTRIDE;     \
    _Pragma("unroll")                                                         \
    for (int k = 0; k < 4; ++k) {                                             \
        const float ux = __uint_as_float(cp_[k * CSTRIDE + 0]);               \
        const float uy = __uint_as_float(cp_[k * CSTRIDE + 1]);               \
        const float uz = __uint_as_float(cp_[k * CSTRIDE + 2]);               \
        const float fc = __uint_as_float(cp_[k * CSTRIDE + 3]);               \
        float W0 = fc * br0;                                                  \
        float W1 = fc * br1;                                                  \
        float W2 = fc * br2;                                                  \
        _Pragma("unroll")                                                     \
        for (int j = 0; j < 10; ++j) {                                        \
            U32H2 cc; cc.u = cp_[k * CSTRIDE + 4 + j];                        \
            U32H2 w0_; w0_.u = wq0[j];                                        \
            U32H2 w1_; w1_.u = wq1[j];                                        \
            U32H2 w2_; w2_.u = wq2[j];                                        \
            W0 = __builtin_amdgcn_fdot2(cc.h, w0_.h, W0, false);              \
            W1 = __builtin_amdgcn_fdot2(cc.h, w1_.h, W1, false);              \
            W2 = __builtin_amdgcn_fdot2(cc.h, w2_.h, W2, false);              \
        }                                                                     \
        const uint32_t p0 = P2[k].x, p1 = P2[k].y, p2 = Pw[k];                \
        const float xv = blo(p0) * W0;                                        \
        const float xs = bhi(p0) * W1;                                        \
        const float xd = blo(p1) * W2;                                        \
        a0 += bhi(p1) * xv + ux * xd;                                         \
        a1 += blo(p2) * xv + uy * xd;                                         \
        a2 += bhi(p2) * xv + uz * xd;                                         \
        as += xs;                                                             \
    }                                                                         \
} while (0)

    if (nb > 0) {
        const int last = nb - 1;
        LOADB(A2, Aw, 0);
        LOADB(B2, Bw, (1 < last ? 1 : last));
        int b = 0;
        for (; b + 2 < nb; b += 2) {
            CONSUME(A2, Aw, b);
            LOADB(A2, Aw, b + 2);
            CONSUME(B2, Bw, b + 1);
            LOADB(B2, Bw, (b + 3 < last ? b + 3 : last));
        }
        const int rem = nb - b;
        CONSUME(A2, Aw, b);
        if (rem == 2) CONSUME(B2, Bw, b + 1);
    }

    // tail (0..3 edges)
    for (int i = beg + (nb << 2); i < end; ++i) {
        const int iu = __builtin_amdgcn_readfirstlane(i);
        const int o = soff[iu] + ch;
        const uint2 P = guv[o];
        const uint32_t p2 = gw[o];
        const uint32_t* cp = coef + (size_t)iu * CSTRIDE;
        const float ux = __uint_as_float(cp[0]);
        const float uy = __uint_as_float(cp[1]);
        const float uz = __uint_as_float(cp[2]);
        const float fc = __uint_as_float(cp[3]);
        float W0 = fc * br0;
        float W1 = fc * br1;
        float W2 = fc * br2;
        #pragma unroll
        for (int j = 0; j < 10; ++j) {
            U32H2 cc; cc.u = cp[4 + j];
            U32H2 w0_; w0_.u = wq0[j];
            U32H2 w1_; w1_.u = wq1[j];
            U32H2 w2_; w2_.u = wq2[j];
            W0 = __builtin_amdgcn_fdot2(cc.h, w0_.h, W0, false);
            W1 = __builtin_amdgcn_fdot2(cc.h, w1_.h, W1, false);
            W2 = __builtin_amdgcn_fdot2(cc.h, w2_.h, W2, false);
        }
        const uint32_t p0 = P.x, p1 = P.y;
        const float xv = blo(p0) * W0;
        const float xs = bhi(p0) * W1;
        const float xd = blo(p1) * W2;
        a0 += bhi(p1) * xv + ux * xd;
        a1 += blo(p2) * xv + uy * xd;
        a2 += bhi(p2) * xv + uz * xd;
        as += xs;
    }

#undef LOADB
#undef CONSUME

    const size_t orow = (size_t)node * 384;
    dv[orow + ch]       = a0;
    dv[orow + 128 + ch] = a1;
    dv[orow + 256 + ch] = a2;
    ds[(size_t)node * HID + ch] = as;
}

extern "C" void kernel_launch(void* const* d_in, const int* in_sizes, int n_in,
                              void* d_out, int out_size, void* d_ws, size_t ws_size,
                              hipStream_t stream)
{
    const float* s    = (const float*)d_in[0];
    const float* v    = (const float*)d_in[1];
    const float* r_ij = (const float*)d_in[2];
    const int*   esrc = (const int*)d_in[3];
    const int*   edst = (const int*)d_in[4];
    const float* W1   = (const float*)d_in[5];
    const float* b1   = (const float*)d_in[6];
    const float* W2   = (const float*)d_in[7];
    const float* b2   = (const float*)d_in[8];
    const float* Wrbf = (const float*)d_in[9];
    const float* brbf = (const float*)d_in[10];

    float* out = (float*)d_out;
    float* dv  = out;                                   // (16384,3,128)
    float* ds  = out + (size_t)N_NODES * 3 * HID;       // (16384,128)

    // workspace layout — pad after row_ptr so row_ptr[16384] cannot alias
    // cur[0] (the R4 crash).
    char* ws = (char*)d_ws;
    uint2*    guv     = (uint2*)   (ws + 0);            // 16,777,216 B
    uint32_t* gw      = (uint32_t*)(ws + 16777216);     //  8,388,608 B
    uint32_t* coef    = (uint32_t*)(ws + 25165824);     // 16,777,216 B
    int*      soff    = (int*)     (ws + 41943040);     //  1,048,576 B
    int*      cnt     = (int*)     (ws + 42991616);     //     65,536 B
    int*      row_ptr = (int*)     (ws + 43057152);     //     65,540 B used
    int*      cur     = (int*)     (ws + 43122816);     //     65,536 B
    uint32_t* W1f     = (uint32_t*)(ws + 43188352);     //     32,768 B
    uint32_t* W2f     = (uint32_t*)(ws + 43221120);     //     98,304 B
    uint32_t* Wrbfp   = (uint32_t*)(ws + 43319424);     //     15,360 B

    hipMemsetAsync(cnt, 0, 16384 * sizeof(int), stream);

    prep_kernel<<<1167, 256, 0, stream>>>(W1, W2, Wrbf, edst, cnt,
                                          W1f, W2f, Wrbfp);
    scan_kernel<<<1, 256, 0, stream>>>(cnt, row_ptr, cur);
    phi_scatter_kernel<<<1024, 256, 0, stream>>>(s, v, W1f, b1, W2f, b2,
                                                 r_ij, esrc, edst, cur,
                                                 soff, coef, guv, gw);
    gather_kernel<<<N_NODES / 2, 256, 0, stream>>>(guv, gw, soff, coef, row_ptr,
                                                   Wrbfp, brbf, dv, ds);
}